// Round 19
// baseline (126.518 us; speedup 1.0000x reference)
//
#include <hip/hip_runtime.h>
#include <cstdint>
#include <cstddef>

#define NB 8
#define NL 2048
#define TOPK 30
#define NH 128
#define CAND_CAP 128
#define EDGE_BLOCKS 1920
#define EDGE_WAVES (EDGE_BLOCKS * 4)

typedef unsigned long long ull;
typedef __attribute__((ext_vector_type(8))) short short8v;   // 8 bf16
typedef __attribute__((ext_vector_type(4))) float f32x4;

__device__ __forceinline__ short f2bf(float f) {
    unsigned int b = __float_as_uint(f);
    b += 0x7fffu + ((b >> 16) & 1u);          // round-to-nearest-even
    return (short)(b >> 16);
}

// bit-exact distance vs numpy: ((dx*dx+dy*dy)+dz*dz)+1e-6, rn sqrt, rn muls.
// Deterministic: both passes call this on the same LDS values -> same bits.
__device__ __forceinline__ void dist_point(const float4 pj,
                                           float xi, float yi, float zi, float mi,
                                           float& d, bool& in) {
    float dx = xi - pj.x;
    float dy = yi - pj.y;
    float dz = zi - pj.z;
    float s = __fadd_rn(__fmul_rn(dx, dx), __fmul_rn(dy, dy));
    s = __fadd_rn(s, __fmul_rn(dz, dz));
    s = __fadd_rn(s, 1e-6f);
    float m2 = __fmul_rn(pj.w, mi);            // binary mask: 0 or 1
    d  = __fmul_rn(m2, __fsqrt_rn(s));
    in = (m2 != 0.0f);
}

// ---------------------------------------------------------------------------
// K1 (topk v12): RECOMPUTE variant -- no u[32] register array. VGPR capped at
// 64 via __launch_bounds__(512,8) -> 8 waves/SIMD (was 4, VGPR~100). 512
// threads = 8 rows/block share one 32 KB LDS stage of (CA,mask) from X.
// Pass 1: lmax (4-chain) + masked-in lane-min, nothing stored. Threshold T =
// 30th-smallest of 64 lane-minima (bitonic) -- provably >= true 30th element.
// P4 recomputes adjusted bits per point (bit-identical) for ballot compaction
// (empty-ballot iterations skipped). P5 rank-based exact selection (cnt<=128
// -> 2 key regs). key=(bits<<32)|j == lax.top_k stable order. Fallback for
// cnt>128: recompute-based iterative exact argmin (rare, correct).
// ---------------------------------------------------------------------------
__global__ __launch_bounds__(512, 8) void topk_kernel(
    const float* __restrict__ X, const float* __restrict__ mask,
    float* __restrict__ eidx, float* __restrict__ dnb)
{
    __shared__ float4 Ps[NL];                      // 32 KB
    __shared__ ull cand[8][CAND_CAP];              // 8 KB

    const int tid = threadIdx.x;
    const int wv  = tid >> 6;                      // 0..7
    const int ln  = tid & 63;
    const int row = blockIdx.x * 8 + wv;           // 8 rows per block
    const int b   = row >> 11;
    const int i   = row & (NL - 1);

    // ---- stage CA coords + mask from X (the block's only barrier) ----
    const float* Xb = X + (size_t)b * NL * 12;
    const float* Mb = mask + (size_t)b * NL;
    #pragma unroll
    for (int q = 0; q < 4; ++q) {
        const int j = tid + 512 * q;
        const float* x = Xb + (size_t)j * 12 + 3;
        Ps[j] = make_float4(x[0], x[1], x[2], Mb[j]);
    }
    __syncthreads();

    const float4 pi = Ps[i];
    const float xi = pi.x, yi = pi.y, zi = pi.z, mi = pi.w;

    // ---- Pass 1: lmax (4-way chains) + masked-in lane-min; nothing stored --
    float lm0 = 0.0f, lm1 = 0.0f, lm2 = 0.0f, lm3 = 0.0f;
    unsigned int umin_in = 0xFFFFFFFFu;
    #pragma unroll
    for (int t = 0; t < 32; t += 4) {
        #pragma unroll
        for (int q = 0; q < 4; ++q) {
            float d; bool in;
            dist_point(Ps[ln + 64 * (t + q)], xi, yi, zi, mi, d, in);
            if (in) umin_in = min(umin_in, __float_as_uint(d));
            if      (q == 0) lm0 = fmaxf(lm0, d);
            else if (q == 1) lm1 = fmaxf(lm1, d);
            else if (q == 2) lm2 = fmaxf(lm2, d);
            else             lm3 = fmaxf(lm3, d);
        }
    }
    float lmax = fmaxf(fmaxf(lm0, lm1), fmaxf(lm2, lm3));
    #pragma unroll
    for (int off = 32; off; off >>= 1) lmax = fmaxf(lmax, __shfl_xor(lmax, off));
    const unsigned int DMB = __float_as_uint(__fadd_rn(lmax, 1.0f));
    // adjusted bits: masked-in -> d bits (< DMB since d <= lmax < lmax+1);
    // masked-out -> exactly DMB. Lane-min of adjusted = umin_in, or DMB if none.
    const unsigned int umin = min(umin_in, DMB);

    // ---- P3: bitonic sort of 64 lane-minima -> threshold T at rank 29 ----
    unsigned int v = umin;
    #pragma unroll
    for (int k = 2; k <= 64; k <<= 1) {
        #pragma unroll
        for (int j = k >> 1; j > 0; j >>= 1) {
            unsigned int o = __shfl_xor(v, j);
            bool asc   = ((ln & k) == 0);
            bool lower = ((ln & j) == 0);
            v = (lower == asc) ? min(v, o) : max(v, o);
        }
    }
    const unsigned int T = __shfl(v, TOPK - 1);

    // ---- P4: recompute + ordered ballot compaction (skip empty ballots) ----
    unsigned int base = 0;
    #pragma unroll
    for (int t = 0; t < 32; ++t) {
        float d; bool in;
        dist_point(Ps[ln + 64 * t], xi, yi, zi, mi, d, in);
        const unsigned int adj = in ? __float_as_uint(d) : DMB;
        const bool act = adj <= T;
        ull m = __ballot(act);
        if (m) {
            if (act) {
                unsigned int pos = base + (unsigned)__popcll(m & ((1ull << ln) - 1ull));
                if (pos < CAND_CAP)
                    cand[wv][pos] = ((ull)adj << 32) | (unsigned)(ln + 64 * t);
            }
            base += (unsigned)__popcll(m);
        }
    }
    const unsigned int cnt = base;

    float* eo  = eidx + (size_t)row * TOPK;
    float* dno = dnb  + (size_t)row * TOPK;

    if (cnt <= CAND_CAP) {
        // ---- P5: rank-based exact selection (cnt <= 128 -> 2 key regs) ----
        ull k0 = ((unsigned)ln       < cnt) ? cand[wv][ln]      : ~0ULL;
        ull k1 = ((unsigned)ln + 64u < cnt) ? cand[wv][ln + 64] : ~0ULL;
        int r0 = 0, r1 = 0;
        for (unsigned int p = 0; p < cnt; p += 4) {
            ull c0 = cand[wv][p];
            ull c1 = (p + 1 < cnt) ? cand[wv][p + 1] : ~0ULL;
            ull c2 = (p + 2 < cnt) ? cand[wv][p + 2] : ~0ULL;
            ull c3 = (p + 3 < cnt) ? cand[wv][p + 3] : ~0ULL;
            r0 += (c0 < k0) + (c1 < k0) + (c2 < k0) + (c3 < k0);
            r1 += (c0 < k1) + (c1 < k1) + (c2 < k1) + (c3 < k1);
        }
        if (r0 < TOPK) { eo[r0] = (float)(unsigned)(k0 & 0xFFFFFFFFu); dno[r0] = __uint_as_float((unsigned)(k0 >> 32)); }
        if (r1 < TOPK) { eo[r1] = (float)(unsigned)(k1 & 0xFFFFFFFFu); dno[r1] = __uint_as_float((unsigned)(k1 >> 32)); }
    } else {
        // ---- fallback: recompute-based iterative exact argmin (rare) ----
        ull last = 0ULL;
        for (int k = 0; k < TOPK; ++k) {
            ull best = ~0ULL;
            #pragma unroll
            for (int t = 0; t < 32; ++t) {
                float d; bool in;
                dist_point(Ps[ln + 64 * t], xi, yi, zi, mi, d, in);
                const unsigned int adj = in ? __float_as_uint(d) : DMB;
                ull key = ((ull)adj << 32) | (unsigned)(ln + 64 * t);
                if (key > last && key < best) best = key;
            }
            #pragma unroll
            for (int off = 32; off; off >>= 1) {
                ull o = __shfl_xor(best, off);
                if (o < best) best = o;
            }
            if (ln == 0) {
                eo[k]  = (float)(unsigned)(best & 0xFFFFFFFFu);
                dno[k] = __uint_as_float((unsigned)(best >> 32));
            }
            last = best;
        }
    }
}

// ---------------------------------------------------------------------------
// K2 (edge ∪ vn, grid-fused -- byte-identical to R17): blocks [0,1920) = edge
// path; blocks [1920,2176) = vn path. Disjoint outputs; order irrelevant.
// ---------------------------------------------------------------------------
__global__ __launch_bounds__(256) void edge_vn_kernel(
    const float* __restrict__ eidx, const float* __restrict__ dnb,
    const float* __restrict__ We, const float* __restrict__ be,
    const float* __restrict__ ge, const float* __restrict__ bte,
    float* __restrict__ E,
    const float* __restrict__ X,  const float* __restrict__ Wn,
    const float* __restrict__ bn, const float* __restrict__ gn,
    const float* __restrict__ btn, float* __restrict__ V)
{
    __shared__ float shmem[4 * 16 * 132];          // 33 KB (edge) / 2 KB (vn)

    const int tid  = threadIdx.x;
    const int lane = tid & 63;
    const int wv   = tid >> 6;

    if (blockIdx.x < EDGE_BLOCKS) {
        // ========================== EDGE PATH ==============================
        float (*ebuf)[132] = (float(*)[132])(shmem + wv * 16 * 132);
        const int c = lane & 15;
        const int g = lane >> 4;
        const int wid = blockIdx.x * 4 + wv;

        short8v W[8];
        #pragma unroll
        for (int t = 0; t < 8; ++t)
            #pragma unroll
            for (int e = 0; e < 8; ++e)
                W[t][e] = f2bf(We[(g * 8 + e) * NH + t * 16 + c]);

        float fcs[8];
        #pragma unroll
        for (int e = 0; e < 8; ++e) {
            if (g < 2) fcs[e] = expf((float)(2 * e) * -0.57564627f);  // ln(1e4)/16
            else       fcs[e] = (float)((g - 2) * 8 + e) * (20.0f / 15.0f);
        }

        const int ntiles = NB * NL * TOPK / 16;
        for (int tile = wid; tile < ntiles; tile += EDGE_WAVES) {
            const int e0   = tile * 16;
            const int edge = e0 + c;
            const float fidx = eidx[edge];
            const float Dv   = dnb[edge];
            const int   row  = edge / TOPK;
            const float d    = fidx - (float)(row & (NL - 1));

            short8v F;
            if (g == 0) {
                #pragma unroll
                for (int e = 0; e < 8; ++e) F[e] = f2bf(cosf(d * fcs[e]));
            } else if (g == 1) {
                #pragma unroll
                for (int e = 0; e < 8; ++e) F[e] = f2bf(sinf(d * fcs[e]));
            } else {
                #pragma unroll
                for (int e = 0; e < 8; ++e) {
                    float tt = (Dv - fcs[e]) * 0.8f;
                    F[e] = f2bf(expf(-tt * tt));
                }
            }

            f32x4 acc[8];
            const f32x4 zero = {0.0f, 0.0f, 0.0f, 0.0f};
            #pragma unroll
            for (int t = 0; t < 8; ++t)
                acc[t] = __builtin_amdgcn_mfma_f32_16x16x32_bf16(W[t], F, zero, 0, 0, 0);

            float s = 0.0f, s2 = 0.0f;
            #pragma unroll
            for (int t = 0; t < 8; ++t) {
                const f32x4 b4 = *(const f32x4*)&be[t * 16 + g * 4];
                #pragma unroll
                for (int j = 0; j < 4; ++j) {
                    float vv = acc[t][j] + b4[j];
                    acc[t][j] = vv;
                    s  += vv;
                    s2 = fmaf(vv, vv, s2);
                }
            }
            s  += __shfl_xor(s, 16);  s  += __shfl_xor(s, 32);
            s2 += __shfl_xor(s2, 16); s2 += __shfl_xor(s2, 32);
            const float mean = s * (1.0f / 128.0f);
            const float var  = fmaxf(s2 * (1.0f / 128.0f) - mean * mean, 0.0f);
            const float inv  = rsqrtf(var + 1e-5f);

            #pragma unroll
            for (int t = 0; t < 8; ++t) {
                const f32x4 g4  = *(const f32x4*)&ge [t * 16 + g * 4];
                const f32x4 bt4 = *(const f32x4*)&bte[t * 16 + g * 4];
                f32x4 o;
                #pragma unroll
                for (int j = 0; j < 4; ++j)
                    o[j] = (acc[t][j] - mean) * inv * g4[j] + bt4[j];
                *(f32x4*)&ebuf[c][t * 16 + g * 4] = o;
            }

            float* const Ebase = E + (size_t)e0 * NH;
            #pragma unroll
            for (int q = 0; q < 8; ++q) {
                const int fi = q * 256 + lane * 4;
                const int ce = fi >> 7;
                const int id = fi & 127;
                const f32x4 o = *(const f32x4*)&ebuf[ce][id];
                __builtin_nontemporal_store(o, (f32x4*)&Ebase[(size_t)ce * NH + id]);
            }
        }
        return;
    }

    // ============================ VN PATH ==================================
    float (*fsh)[8] = (float(*)[8])shmem;          // [64][8]
    const int node_base = (blockIdx.x - EDGE_BLOCKS) * 64;

    if (tid < 64) {
        const int ln   = tid;
        const int node = node_base + ln;
        const int b = node >> 11, i = node & (NL - 1);

        const int h0 = ln, h1 = ln + 64;
        float w0[6], w1[6];
        #pragma unroll
        for (int j = 0; j < 6; ++j) { w0[j] = Wn[j * NH + h0]; w1[j] = Wn[j * NH + h1]; }
        const float bb0 = bn[h0], bb1 = bn[h1];

        // Phase 0: wave-reduce LN stats (35 values)
        float st[35];
        {
            int idx = 0;
            #pragma unroll
            for (int j = 0; j < 6; ++j)
                #pragma unroll
                for (int k = j; k < 6; ++k)
                    st[idx++] = w0[j] * w0[k] + w1[j] * w1[k];
            #pragma unroll
            for (int j = 0; j < 6; ++j) st[21 + j] = w0[j] * bb0 + w1[j] * bb1;
            #pragma unroll
            for (int j = 0; j < 6; ++j) st[27 + j] = w0[j] + w1[j];
            st[33] = bb0 + bb1;
            st[34] = bb0 * bb0 + bb1 * bb1;
            #pragma unroll
            for (int q = 0; q < 35; ++q) {
                float vv = st[q];
                #pragma unroll
                for (int off = 32; off; off >>= 1) vv += __shfl_xor(vv, off);
                st[q] = vv;
            }
        }

        // Phase 1: dihedrals for THIS lane's node
        const float* XB = X + (size_t)b * NL * 12;
        const int rm1 = (i >= 1) ? i - 1 : 0;
        const int rp1 = (i <= NL - 2) ? i + 1 : NL - 1;
        float p[6][3];
        {
            const int rows[6]  = { rm1, i, i, i, rp1, rp1 };
            const int atoms[6] = { 2,   0, 1, 2, 0,   1   };
            #pragma unroll
            for (int k = 0; k < 6; ++k) {
                const float* q = XB + ((size_t)rows[k] * 4 + atoms[k]) * 3;
                p[k][0] = q[0]; p[k][1] = q[1]; p[k][2] = q[2];
            }
        }
        float uv[5][3], nv[4][3];
        #pragma unroll
        for (int k = 0; k < 5; ++k) {
            float vx = p[k+1][0] - p[k][0];
            float vy = p[k+1][1] - p[k][1];
            float vz = p[k+1][2] - p[k][2];
            float n = sqrtf(vx*vx + vy*vy + vz*vz) + 1e-8f;
            uv[k][0] = vx / n; uv[k][1] = vy / n; uv[k][2] = vz / n;
        }
        #pragma unroll
        for (int k = 0; k < 4; ++k) {
            float cx = uv[k][1]*uv[k+1][2] - uv[k][2]*uv[k+1][1];
            float cy = uv[k][2]*uv[k+1][0] - uv[k][0]*uv[k+1][2];
            float cz = uv[k][0]*uv[k+1][1] - uv[k][1]*uv[k+1][0];
            float n = sqrtf(cx*cx + cy*cy + cz*cz) + 1e-8f;
            nv[k][0] = cx / n; nv[k][1] = cy / n; nv[k][2] = cz / n;
        }
        float f[6];
        #pragma unroll
        for (int a = 0; a < 3; ++a) {
            bool valid = (a == 0) ? (i >= 1) : (i <= NL - 2);
            float cosD = nv[a][0]*nv[a+1][0] + nv[a][1]*nv[a+1][1] + nv[a][2]*nv[a+1][2];
            cosD = fminf(fmaxf(cosD, -1.0f + 1e-7f), 1.0f - 1e-7f);
            float sg = uv[a][0]*nv[a+1][0] + uv[a][1]*nv[a+1][1] + uv[a][2]*nv[a+1][2];
            float sgn = (sg > 0.0f) ? 1.0f : ((sg < 0.0f) ? -1.0f : 0.0f);
            float an = valid ? (sgn * acosf(cosD)) : 0.0f;
            f[a]     = cosf(an);
            f[3 + a] = sinf(an);
        }

        float s1 = st[33];
        #pragma unroll
        for (int j = 0; j < 6; ++j) s1 = fmaf(f[j], st[27 + j], s1);
        float qd = st[34];
        #pragma unroll
        for (int j = 0; j < 6; ++j) qd = fmaf(2.0f * f[j], st[21 + j], qd);
        {
            int idx = 0;
            #pragma unroll
            for (int j = 0; j < 6; ++j)
                #pragma unroll
                for (int k = j; k < 6; ++k) {
                    float coef = (j == k) ? 1.0f : 2.0f;
                    qd = fmaf(coef * f[j] * f[k], st[idx], qd);
                    ++idx;
                }
        }
        const float mean = s1 * (1.0f / 128.0f);
        const float var  = fmaxf(qd * (1.0f / 128.0f) - mean * mean, 0.0f);
        const float inv  = rsqrtf(var + 1e-5f);

        #pragma unroll
        for (int j = 0; j < 6; ++j) fsh[ln][j] = f[j];
        fsh[ln][6] = mean;
        fsh[ln][7] = inv;
    }
    __syncthreads();

    // Phase 2: all 256 threads; 4 h-cols each; coalesced f32x4 stores
    const int m  = tid & 31;
    const int ng = tid >> 5;
    const int h4 = m * 4;
    f32x4 w4[6];
    #pragma unroll
    for (int j = 0; j < 6; ++j) w4[j] = *(const f32x4*)&Wn[j * NH + h4];
    const f32x4 b4  = *(const f32x4*)&bn [h4];
    const f32x4 g4  = *(const f32x4*)&gn [h4];
    const f32x4 bt4 = *(const f32x4*)&btn[h4];

    #pragma unroll
    for (int it = 0; it < 8; ++it) {
        const int nn = it * 8 + ng;
        const float* fr = fsh[nn];
        f32x4 a = b4;
        #pragma unroll
        for (int j = 0; j < 6; ++j) {
            const float fj = fr[j];
            #pragma unroll
            for (int x = 0; x < 4; ++x) a[x] = fmaf(fj, w4[j][x], a[x]);
        }
        const float mn = fr[6], iv = fr[7];
        f32x4 o;
        #pragma unroll
        for (int x = 0; x < 4; ++x) o[x] = (a[x] - mn) * iv * g4[x] + bt4[x];
        *(f32x4*)&V[(size_t)(node_base + nn) * NH + h4] = o;
    }
}

extern "C" void kernel_launch(void* const* d_in, const int* in_sizes, int n_in,
                              void* d_out, int out_size, void* d_ws, size_t ws_size,
                              hipStream_t stream)
{
    const float* X    = (const float*)d_in[0];
    const float* mask = (const float*)d_in[1];
    const float* Wn   = (const float*)d_in[2];
    const float* bn   = (const float*)d_in[3];
    const float* We   = (const float*)d_in[4];
    const float* be   = (const float*)d_in[5];
    const float* gn   = (const float*)d_in[6];
    const float* btn  = (const float*)d_in[7];
    const float* ge   = (const float*)d_in[8];
    const float* bte  = (const float*)d_in[9];

    float* out = (float*)d_out;
    float* V   = out;                                   // (8,2048,128)
    float* E   = V  + (size_t)NB * NL * NH;             // (8,2048,30,128)
    float* EI  = E  + (size_t)NB * NL * TOPK * NH;      // (8,2048,30) as float

    float* dnb = (float*)d_ws;                          // D_neighbors scratch

    hipLaunchKernelGGL(topk_kernel,    dim3(NB * NL / 8),       dim3(512), 0, stream,
                       X, mask, EI, dnb);
    hipLaunchKernelGGL(edge_vn_kernel, dim3(EDGE_BLOCKS + 256), dim3(256), 0, stream,
                       EI, dnb, We, be, ge, bte, E, X, Wn, bn, gn, btn, V);
}

// Round 20
// 113.394 us; speedup vs baseline: 1.1157x; 1.1157x over previous
//
#include <hip/hip_runtime.h>
#include <cstdint>
#include <cstddef>

#define NB 8
#define NL 2048
#define TOPK 30
#define NH 128
#define CAND_CAP 256
#define EDGE_BLOCKS 1920
#define EDGE_WAVES (EDGE_BLOCKS * 4)

typedef unsigned long long ull;
typedef __attribute__((ext_vector_type(8))) short short8v;   // 8 bf16
typedef __attribute__((ext_vector_type(4))) float f32x4;

__device__ __forceinline__ short f2bf(float f) {
    unsigned int b = __float_as_uint(f);
    b += 0x7fffu + ((b >> 16) & 1u);          // round-to-nearest-even
    return (short)(b >> 16);
}

// ---------------------------------------------------------------------------
// K1 (topk v9, byte-identical to R17 -- measured best): 512-thread blocks;
// 8 rows share ONE 32 KB LDS stage, loaded straight from X+mask (bit-exact
// distances: ((dx*dx+dy*dy)+dz*dz)+1e-6, rn sqrt/muls). Selection: bitonic
// lane-min threshold, ballot compaction, rank-based exact selection;
// key=(bits<<32)|j == lax.top_k stable order; exact fallback on overflow.
// ---------------------------------------------------------------------------
__global__ __launch_bounds__(512) void topk_kernel(
    const float* __restrict__ X, const float* __restrict__ mask,
    float* __restrict__ eidx, float* __restrict__ dnb)
{
    __shared__ float4 Ps[NL];                      // 32 KB
    __shared__ ull cand[8][CAND_CAP];              // 16 KB

    const int tid = threadIdx.x;
    const int wv  = tid >> 6;                      // 0..7
    const int ln  = tid & 63;
    const int row = blockIdx.x * 8 + wv;           // 8 rows per block
    const int b   = row >> 11;
    const int i   = row & (NL - 1);

    // ---- stage CA coords + mask from X (the block's only barrier) ----
    const float* Xb = X + (size_t)b * NL * 12;
    const float* Mb = mask + (size_t)b * NL;
    #pragma unroll
    for (int q = 0; q < 4; ++q) {
        const int j = tid + 512 * q;
        const float* x = Xb + (size_t)j * 12 + 3;
        Ps[j] = make_float4(x[0], x[1], x[2], Mb[j]);
    }
    __syncthreads();

    const float4 pi = Ps[i];
    const float xi = pi.x, yi = pi.y, zi = pi.z, mi = pi.w;

    // ---- P1: distances once from LDS; mask flag in sign bit; 4-way chains --
    unsigned int u[32];
    float lm0 = 0.0f, lm1 = 0.0f, lm2 = 0.0f, lm3 = 0.0f;
    #pragma unroll
    for (int t = 0; t < 32; t += 4) {
        #pragma unroll
        for (int q = 0; q < 4; ++q) {
            const float4 pj = Ps[ln + 64 * (t + q)];
            float dx = xi - pj.x;
            float dy = yi - pj.y;
            float dz = zi - pj.z;
            float s = __fadd_rn(__fmul_rn(dx, dx), __fmul_rn(dy, dy));
            s = __fadd_rn(s, __fmul_rn(dz, dz));
            s = __fadd_rn(s, 1e-6f);
            float m2 = __fmul_rn(pj.w, mi);
            float d  = __fmul_rn(m2, __fsqrt_rn(s));
            u[t + q] = __float_as_uint(d) | ((m2 == 0.0f) ? 0x80000000u : 0u);
            if      (q == 0) lm0 = fmaxf(lm0, d);
            else if (q == 1) lm1 = fmaxf(lm1, d);
            else if (q == 2) lm2 = fmaxf(lm2, d);
            else             lm3 = fmaxf(lm3, d);
        }
    }
    float lmax = fmaxf(fmaxf(lm0, lm1), fmaxf(lm2, lm3));
    #pragma unroll
    for (int off = 32; off; off >>= 1) lmax = fmaxf(lmax, __shfl_xor(lmax, off));
    const unsigned int DMB = __float_as_uint(__fadd_rn(lmax, 1.0f));

    // ---- P2: adjusted bits via select + per-lane min (4-way chains) ----
    unsigned int um0 = 0xFFFFFFFFu, um1 = 0xFFFFFFFFu,
                 um2 = 0xFFFFFFFFu, um3 = 0xFFFFFFFFu;
    #pragma unroll
    for (int t = 0; t < 32; t += 4) {
        unsigned int b0 = (u[t+0] & 0x80000000u) ? DMB : u[t+0];
        unsigned int b1 = (u[t+1] & 0x80000000u) ? DMB : u[t+1];
        unsigned int b2 = (u[t+2] & 0x80000000u) ? DMB : u[t+2];
        unsigned int b3 = (u[t+3] & 0x80000000u) ? DMB : u[t+3];
        u[t+0] = b0; u[t+1] = b1; u[t+2] = b2; u[t+3] = b3;
        um0 = min(um0, b0); um1 = min(um1, b1);
        um2 = min(um2, b2); um3 = min(um3, b3);
    }
    unsigned int umin = min(min(um0, um1), min(um2, um3));

    // ---- P3: bitonic sort of 64 lane-minima -> threshold T at rank 29 ----
    unsigned int v = umin;
    #pragma unroll
    for (int k = 2; k <= 64; k <<= 1) {
        #pragma unroll
        for (int j = k >> 1; j > 0; j >>= 1) {
            unsigned int o = __shfl_xor(v, j);
            bool asc   = ((ln & k) == 0);
            bool lower = ((ln & j) == 0);
            v = (lower == asc) ? min(v, o) : max(v, o);
        }
    }
    const unsigned int T = __shfl(v, TOPK - 1);

    // ---- P4: ordered ballot compaction ----
    unsigned int base = 0;
    #pragma unroll
    for (int t = 0; t < 32; ++t) {
        bool act = u[t] <= T;
        ull m = __ballot(act);
        if (act) {
            unsigned int pos = base + (unsigned)__popcll(m & ((1ull << ln) - 1ull));
            if (pos < CAND_CAP)
                cand[wv][pos] = ((ull)u[t] << 32) | (unsigned)(ln + 64 * t);
        }
        base += (unsigned)__popcll(m);
    }
    const unsigned int cnt = base;

    float* eo  = eidx + (size_t)row * TOPK;
    float* dno = dnb  + (size_t)row * TOPK;

    if (cnt <= CAND_CAP) {
        // ---- P5: rank-based exact selection, unrolled x4 ----
        ull k0 = ((unsigned)ln        < cnt) ? cand[wv][ln]        : ~0ULL;
        ull k1 = ((unsigned)ln +  64u < cnt) ? cand[wv][ln +  64]  : ~0ULL;
        ull k2 = ((unsigned)ln + 128u < cnt) ? cand[wv][ln + 128]  : ~0ULL;
        ull k3 = ((unsigned)ln + 192u < cnt) ? cand[wv][ln + 192]  : ~0ULL;
        int r0 = 0, r1 = 0, r2 = 0, r3 = 0;
        for (unsigned int p = 0; p < cnt; p += 4) {
            ull c0 = cand[wv][p];
            ull c1 = (p + 1 < cnt) ? cand[wv][p + 1] : ~0ULL;
            ull c2 = (p + 2 < cnt) ? cand[wv][p + 2] : ~0ULL;
            ull c3 = (p + 3 < cnt) ? cand[wv][p + 3] : ~0ULL;
            r0 += (c0 < k0) + (c1 < k0) + (c2 < k0) + (c3 < k0);
            r1 += (c0 < k1) + (c1 < k1) + (c2 < k1) + (c3 < k1);
            r2 += (c0 < k2) + (c1 < k2) + (c2 < k2) + (c3 < k2);
            r3 += (c0 < k3) + (c1 < k3) + (c2 < k3) + (c3 < k3);
        }
        if (r0 < TOPK) { eo[r0] = (float)(unsigned)(k0 & 0xFFFFFFFFu); dno[r0] = __uint_as_float((unsigned)(k0 >> 32)); }
        if (r1 < TOPK) { eo[r1] = (float)(unsigned)(k1 & 0xFFFFFFFFu); dno[r1] = __uint_as_float((unsigned)(k1 >> 32)); }
        if (r2 < TOPK) { eo[r2] = (float)(unsigned)(k2 & 0xFFFFFFFFu); dno[r2] = __uint_as_float((unsigned)(k2 >> 32)); }
        if (r3 < TOPK) { eo[r3] = (float)(unsigned)(k3 & 0xFFFFFFFFu); dno[r3] = __uint_as_float((unsigned)(k3 >> 32)); }
    } else {
        // ---- fallback: wave-iterative exact argmin from registers (rare) ----
        ull last = 0ULL;
        for (int k = 0; k < TOPK; ++k) {
            ull best = ~0ULL;
            #pragma unroll
            for (int t = 0; t < 32; ++t) {
                ull key = ((ull)u[t] << 32) | (unsigned)(ln + 64 * t);
                if (key > last && key < best) best = key;
            }
            #pragma unroll
            for (int off = 32; off; off >>= 1) {
                ull o = __shfl_xor(best, off);
                if (o < best) best = o;
            }
            if (ln == 0) {
                eo[k]  = (float)(unsigned)(best & 0xFFFFFFFFu);
                dno[k] = __uint_as_float((unsigned)(best >> 32));
            }
            last = best;
        }
    }
}

// ---------------------------------------------------------------------------
// K2 (edge ∪ vn, grid-fused -- byte-identical to R17): blocks [0,1920) = edge
// path; blocks [1920,2176) = vn path. Disjoint outputs; order irrelevant.
// ---------------------------------------------------------------------------
__global__ __launch_bounds__(256) void edge_vn_kernel(
    const float* __restrict__ eidx, const float* __restrict__ dnb,
    const float* __restrict__ We, const float* __restrict__ be,
    const float* __restrict__ ge, const float* __restrict__ bte,
    float* __restrict__ E,
    const float* __restrict__ X,  const float* __restrict__ Wn,
    const float* __restrict__ bn, const float* __restrict__ gn,
    const float* __restrict__ btn, float* __restrict__ V)
{
    __shared__ float shmem[4 * 16 * 132];          // 33 KB (edge) / 2 KB (vn)

    const int tid  = threadIdx.x;
    const int lane = tid & 63;
    const int wv   = tid >> 6;

    if (blockIdx.x < EDGE_BLOCKS) {
        // ========================== EDGE PATH ==============================
        float (*ebuf)[132] = (float(*)[132])(shmem + wv * 16 * 132);
        const int c = lane & 15;
        const int g = lane >> 4;
        const int wid = blockIdx.x * 4 + wv;

        short8v W[8];
        #pragma unroll
        for (int t = 0; t < 8; ++t)
            #pragma unroll
            for (int e = 0; e < 8; ++e)
                W[t][e] = f2bf(We[(g * 8 + e) * NH + t * 16 + c]);

        float fcs[8];
        #pragma unroll
        for (int e = 0; e < 8; ++e) {
            if (g < 2) fcs[e] = expf((float)(2 * e) * -0.57564627f);  // ln(1e4)/16
            else       fcs[e] = (float)((g - 2) * 8 + e) * (20.0f / 15.0f);
        }

        const int ntiles = NB * NL * TOPK / 16;
        for (int tile = wid; tile < ntiles; tile += EDGE_WAVES) {
            const int e0   = tile * 16;
            const int edge = e0 + c;
            const float fidx = eidx[edge];
            const float Dv   = dnb[edge];
            const int   row  = edge / TOPK;
            const float d    = fidx - (float)(row & (NL - 1));

            short8v F;
            if (g == 0) {
                #pragma unroll
                for (int e = 0; e < 8; ++e) F[e] = f2bf(cosf(d * fcs[e]));
            } else if (g == 1) {
                #pragma unroll
                for (int e = 0; e < 8; ++e) F[e] = f2bf(sinf(d * fcs[e]));
            } else {
                #pragma unroll
                for (int e = 0; e < 8; ++e) {
                    float tt = (Dv - fcs[e]) * 0.8f;
                    F[e] = f2bf(expf(-tt * tt));
                }
            }

            f32x4 acc[8];
            const f32x4 zero = {0.0f, 0.0f, 0.0f, 0.0f};
            #pragma unroll
            for (int t = 0; t < 8; ++t)
                acc[t] = __builtin_amdgcn_mfma_f32_16x16x32_bf16(W[t], F, zero, 0, 0, 0);

            float s = 0.0f, s2 = 0.0f;
            #pragma unroll
            for (int t = 0; t < 8; ++t) {
                const f32x4 b4 = *(const f32x4*)&be[t * 16 + g * 4];
                #pragma unroll
                for (int j = 0; j < 4; ++j) {
                    float vv = acc[t][j] + b4[j];
                    acc[t][j] = vv;
                    s  += vv;
                    s2 = fmaf(vv, vv, s2);
                }
            }
            s  += __shfl_xor(s, 16);  s  += __shfl_xor(s, 32);
            s2 += __shfl_xor(s2, 16); s2 += __shfl_xor(s2, 32);
            const float mean = s * (1.0f / 128.0f);
            const float var  = fmaxf(s2 * (1.0f / 128.0f) - mean * mean, 0.0f);
            const float inv  = rsqrtf(var + 1e-5f);

            #pragma unroll
            for (int t = 0; t < 8; ++t) {
                const f32x4 g4  = *(const f32x4*)&ge [t * 16 + g * 4];
                const f32x4 bt4 = *(const f32x4*)&bte[t * 16 + g * 4];
                f32x4 o;
                #pragma unroll
                for (int j = 0; j < 4; ++j)
                    o[j] = (acc[t][j] - mean) * inv * g4[j] + bt4[j];
                *(f32x4*)&ebuf[c][t * 16 + g * 4] = o;
            }

            float* const Ebase = E + (size_t)e0 * NH;
            #pragma unroll
            for (int q = 0; q < 8; ++q) {
                const int fi = q * 256 + lane * 4;
                const int ce = fi >> 7;
                const int id = fi & 127;
                const f32x4 o = *(const f32x4*)&ebuf[ce][id];
                __builtin_nontemporal_store(o, (f32x4*)&Ebase[(size_t)ce * NH + id]);
            }
        }
        return;
    }

    // ============================ VN PATH ==================================
    float (*fsh)[8] = (float(*)[8])shmem;          // [64][8]
    const int node_base = (blockIdx.x - EDGE_BLOCKS) * 64;

    if (tid < 64) {
        const int ln   = tid;
        const int node = node_base + ln;
        const int b = node >> 11, i = node & (NL - 1);

        const int h0 = ln, h1 = ln + 64;
        float w0[6], w1[6];
        #pragma unroll
        for (int j = 0; j < 6; ++j) { w0[j] = Wn[j * NH + h0]; w1[j] = Wn[j * NH + h1]; }
        const float bb0 = bn[h0], bb1 = bn[h1];

        // Phase 0: wave-reduce LN stats (35 values)
        float st[35];
        {
            int idx = 0;
            #pragma unroll
            for (int j = 0; j < 6; ++j)
                #pragma unroll
                for (int k = j; k < 6; ++k)
                    st[idx++] = w0[j] * w0[k] + w1[j] * w1[k];
            #pragma unroll
            for (int j = 0; j < 6; ++j) st[21 + j] = w0[j] * bb0 + w1[j] * bb1;
            #pragma unroll
            for (int j = 0; j < 6; ++j) st[27 + j] = w0[j] + w1[j];
            st[33] = bb0 + bb1;
            st[34] = bb0 * bb0 + bb1 * bb1;
            #pragma unroll
            for (int q = 0; q < 35; ++q) {
                float vv = st[q];
                #pragma unroll
                for (int off = 32; off; off >>= 1) vv += __shfl_xor(vv, off);
                st[q] = vv;
            }
        }

        // Phase 1: dihedrals for THIS lane's node
        const float* XB = X + (size_t)b * NL * 12;
        const int rm1 = (i >= 1) ? i - 1 : 0;
        const int rp1 = (i <= NL - 2) ? i + 1 : NL - 1;
        float p[6][3];
        {
            const int rows[6]  = { rm1, i, i, i, rp1, rp1 };
            const int atoms[6] = { 2,   0, 1, 2, 0,   1   };
            #pragma unroll
            for (int k = 0; k < 6; ++k) {
                const float* q = XB + ((size_t)rows[k] * 4 + atoms[k]) * 3;
                p[k][0] = q[0]; p[k][1] = q[1]; p[k][2] = q[2];
            }
        }
        float uv[5][3], nv[4][3];
        #pragma unroll
        for (int k = 0; k < 5; ++k) {
            float vx = p[k+1][0] - p[k][0];
            float vy = p[k+1][1] - p[k][1];
            float vz = p[k+1][2] - p[k][2];
            float n = sqrtf(vx*vx + vy*vy + vz*vz) + 1e-8f;
            uv[k][0] = vx / n; uv[k][1] = vy / n; uv[k][2] = vz / n;
        }
        #pragma unroll
        for (int k = 0; k < 4; ++k) {
            float cx = uv[k][1]*uv[k+1][2] - uv[k][2]*uv[k+1][1];
            float cy = uv[k][2]*uv[k+1][0] - uv[k][0]*uv[k+1][2];
            float cz = uv[k][0]*uv[k+1][1] - uv[k][1]*uv[k+1][0];
            float n = sqrtf(cx*cx + cy*cy + cz*cz) + 1e-8f;
            nv[k][0] = cx / n; nv[k][1] = cy / n; nv[k][2] = cz / n;
        }
        float f[6];
        #pragma unroll
        for (int a = 0; a < 3; ++a) {
            bool valid = (a == 0) ? (i >= 1) : (i <= NL - 2);
            float cosD = nv[a][0]*nv[a+1][0] + nv[a][1]*nv[a+1][1] + nv[a][2]*nv[a+1][2];
            cosD = fminf(fmaxf(cosD, -1.0f + 1e-7f), 1.0f - 1e-7f);
            float sg = uv[a][0]*nv[a+1][0] + uv[a][1]*nv[a+1][1] + uv[a][2]*nv[a+1][2];
            float sgn = (sg > 0.0f) ? 1.0f : ((sg < 0.0f) ? -1.0f : 0.0f);
            float an = valid ? (sgn * acosf(cosD)) : 0.0f;
            f[a]     = cosf(an);
            f[3 + a] = sinf(an);
        }

        float s1 = st[33];
        #pragma unroll
        for (int j = 0; j < 6; ++j) s1 = fmaf(f[j], st[27 + j], s1);
        float qd = st[34];
        #pragma unroll
        for (int j = 0; j < 6; ++j) qd = fmaf(2.0f * f[j], st[21 + j], qd);
        {
            int idx = 0;
            #pragma unroll
            for (int j = 0; j < 6; ++j)
                #pragma unroll
                for (int k = j; k < 6; ++k) {
                    float coef = (j == k) ? 1.0f : 2.0f;
                    qd = fmaf(coef * f[j] * f[k], st[idx], qd);
                    ++idx;
                }
        }
        const float mean = s1 * (1.0f / 128.0f);
        const float var  = fmaxf(qd * (1.0f / 128.0f) - mean * mean, 0.0f);
        const float inv  = rsqrtf(var + 1e-5f);

        #pragma unroll
        for (int j = 0; j < 6; ++j) fsh[ln][j] = f[j];
        fsh[ln][6] = mean;
        fsh[ln][7] = inv;
    }
    __syncthreads();

    // Phase 2: all 256 threads; 4 h-cols each; coalesced f32x4 stores
    const int m  = tid & 31;
    const int ng = tid >> 5;
    const int h4 = m * 4;
    f32x4 w4[6];
    #pragma unroll
    for (int j = 0; j < 6; ++j) w4[j] = *(const f32x4*)&Wn[j * NH + h4];
    const f32x4 b4  = *(const f32x4*)&bn [h4];
    const f32x4 g4  = *(const f32x4*)&gn [h4];
    const f32x4 bt4 = *(const f32x4*)&btn[h4];

    #pragma unroll
    for (int it = 0; it < 8; ++it) {
        const int nn = it * 8 + ng;
        const float* fr = fsh[nn];
        f32x4 a = b4;
        #pragma unroll
        for (int j = 0; j < 6; ++j) {
            const float fj = fr[j];
            #pragma unroll
            for (int x = 0; x < 4; ++x) a[x] = fmaf(fj, w4[j][x], a[x]);
        }
        const float mn = fr[6], iv = fr[7];
        f32x4 o;
        #pragma unroll
        for (int x = 0; x < 4; ++x) o[x] = (a[x] - mn) * iv * g4[x] + bt4[x];
        *(f32x4*)&V[(size_t)(node_base + nn) * NH + h4] = o;
    }
}

extern "C" void kernel_launch(void* const* d_in, const int* in_sizes, int n_in,
                              void* d_out, int out_size, void* d_ws, size_t ws_size,
                              hipStream_t stream)
{
    const float* X    = (const float*)d_in[0];
    const float* mask = (const float*)d_in[1];
    const float* Wn   = (const float*)d_in[2];
    const float* bn   = (const float*)d_in[3];
    const float* We   = (const float*)d_in[4];
    const float* be   = (const float*)d_in[5];
    const float* gn   = (const float*)d_in[6];
    const float* btn  = (const float*)d_in[7];
    const float* ge   = (const float*)d_in[8];
    const float* bte  = (const float*)d_in[9];

    float* out = (float*)d_out;
    float* V   = out;                                   // (8,2048,128)
    float* E   = V  + (size_t)NB * NL * NH;             // (8,2048,30,128)
    float* EI  = E  + (size_t)NB * NL * TOPK * NH;      // (8,2048,30) as float

    float* dnb = (float*)d_ws;                          // D_neighbors scratch

    hipLaunchKernelGGL(topk_kernel,    dim3(NB * NL / 8),       dim3(512), 0, stream,
                       X, mask, EI, dnb);
    hipLaunchKernelGGL(edge_vn_kernel, dim3(EDGE_BLOCKS + 256), dim3(256), 0, stream,
                       EI, dnb, We, be, ge, bte, E, X, Wn, bn, gn, btn, V);
}